// Round 3
// baseline (346.299 us; speedup 1.0000x reference)
//
#include <hip/hip_runtime.h>
#include <math.h>

#define EPS 1e-6f
#define C 1604
#define B 16384
#define C4 401                   // C/4 exact
#define ROWS_PER_BLOCK 4
#define BLOCK 256                // 4 waves -> 4 rows
#define GRID (B / ROWS_PER_BLOCK) // 4096
#define NBUCKETS 64
#define TAIL_LANES (C4 - 6 * 64) // 17

typedef __attribute__((ext_vector_type(4))) float f32x4;

// Fused: one WAVE per row (no LDS reductions for the row math), per-block
// partial -> 64 spread atomic buckets, last-arriving block does the final
// 64-element sum and writes the mean. Single kernel + one 4B/256B memset node.
__global__ __launch_bounds__(BLOCK) void seesaw_fused_kernel(
    const float* __restrict__ logits,
    const float* __restrict__ s,
    const int*   __restrict__ targets,
    float*       __restrict__ out,
    float*       __restrict__ buckets,      // [NBUCKETS], zeroed by memset
    unsigned int* __restrict__ counter)     // zeroed by memset
{
    const int wave = threadIdx.x >> 6;
    const int lane = threadIdx.x & 63;
    const int b = blockIdx.x * ROWS_PER_BLOCK + wave;
    const int t = targets[b];

    const f32x4* lrow = (const f32x4*)(logits + (size_t)b * C);
    const f32x4* srow = (const f32x4*)(s + (size_t)t * C);

    // ---- issue all loads up front; logits nontemporal (pure streaming) ----
    f32x4 lv[7], sv[7];
    #pragma unroll
    for (int k = 0; k < 6; ++k) lv[k] = __builtin_nontemporal_load(&lrow[lane + 64 * k]);
    #pragma unroll
    for (int k = 0; k < 6; ++k) sv[k] = srow[lane + 64 * k];
    const bool tail = lane < TAIL_LANES;
    if (tail) {
        lv[6] = __builtin_nontemporal_load(&lrow[lane + 384]);
        sv[6] = srow[lane + 384];
    } else {
        lv[6] = (f32x4){-INFINITY, -INFINITY, -INFINITY, -INFINITY};
        sv[6] = (f32x4){0.f, 0.f, 0.f, 0.f};
    }

    // ---- row max: per-lane then 6-step butterfly ----
    float m = -INFINITY;
    #pragma unroll
    for (int k = 0; k < 7; ++k)
        m = fmaxf(m, fmaxf(fmaxf(lv[k].x, lv[k].y), fmaxf(lv[k].z, lv[k].w)));
    #pragma unroll
    for (int off = 32; off > 0; off >>= 1)
        m = fmaxf(m, __shfl_xor(m, off, 64));

    // ---- denom partial + target-logit capture ----
    float p = 0.f;
    float lt_local = 0.f;
    #pragma unroll
    for (int k = 0; k < 7; ++k) {
        const int j = (lane + 64 * k) << 2;
        const bool e0 = (j     == t);
        const bool e1 = (j + 1 == t);
        const bool e2 = (j + 2 == t);
        const bool e3 = (j + 3 == t);
        p += __expf(lv[k].x - m) * (e0 ? 1.f : sv[k].x);
        p += __expf(lv[k].y - m) * (e1 ? 1.f : sv[k].y);
        p += __expf(lv[k].z - m) * (e2 ? 1.f : sv[k].z);
        p += __expf(lv[k].w - m) * (e3 ? 1.f : sv[k].w);
        if (e0) lt_local = lv[k].x;
        if (e1) lt_local = lv[k].y;
        if (e2) lt_local = lv[k].z;
        if (e3) lt_local = lv[k].w;
    }
    #pragma unroll
    for (int off = 32; off > 0; off >>= 1)
        p += __shfl_xor(p, off, 64);

    const float lt = __shfl(lt_local, (t >> 2) & 63, 64);

    // ---- per-wave loss -> block partial -> spread atomic bucket ----
    __shared__ float wsum[ROWS_PER_BLOCK];
    __shared__ int   s_last;
    if (lane == 0) {
        const float numt  = __expf(lt - m);
        const float sigma = numt / (p + EPS);
        wsum[wave] = -logf(sigma + EPS);
    }
    __syncthreads();
    if (threadIdx.x == 0) {
        const float bsum = (wsum[0] + wsum[1]) + (wsum[2] + wsum[3]);
        atomicAdd(&buckets[blockIdx.x & (NBUCKETS - 1)], bsum);
        __threadfence();                       // publish bucket before counter
        const unsigned old = atomicAdd(counter, 1u);
        s_last = (old == GRID - 1);
    }
    __syncthreads();

    // ---- last block finalizes: 64 lanes read 64 buckets coherently ----
    if (s_last && wave == 0) {
        float v = __hip_atomic_load(&buckets[lane], __ATOMIC_RELAXED,
                                    __HIP_MEMORY_SCOPE_AGENT);
        #pragma unroll
        for (int off = 32; off > 0; off >>= 1)
            v += __shfl_xor(v, off, 64);
        if (lane == 0)
            out[0] = v * (1.0f / B);
    }
}

extern "C" void kernel_launch(void* const* d_in, const int* in_sizes, int n_in,
                              void* d_out, int out_size, void* d_ws, size_t ws_size,
                              hipStream_t stream) {
    const float* logits  = (const float*)d_in[0];
    const float* s       = (const float*)d_in[1];
    const int*   targets = (const int*)d_in[2];
    float* out = (float*)d_out;

    float* buckets        = (float*)d_ws;                       // 64 floats
    unsigned int* counter = (unsigned int*)((char*)d_ws + 256); // 1 uint

    hipMemsetAsync(d_ws, 0, 512, stream);  // zero buckets + counter (capturable)
    seesaw_fused_kernel<<<GRID, BLOCK, 0, stream>>>(logits, s, targets, out,
                                                    buckets, counter);
}